// Round 1
// 2333.682 us; speedup vs baseline: 1.0246x; 1.0246x over previous
//
#include <hip/hip_runtime.h>
#include <math.h>

namespace {
constexpr int Bn = 8, Tn = 4096, Hn = 4, HVn = 8, Kn = 128, Vn = 128;
constexpr int DEPTH = 4;                        // register prefetch depth
constexpr float SCALE = 0.088388347648318447f;  // 128^-0.5
}

// ---------------- low-latency cross-lane reductions ----------------
// __shfl_xor lowers to ds_bpermute (~120cy DS latency). For the loop-carried
// reduction we use VALU-class ops instead:
//   xor1/2  : DPP quad_perm          (prepass only)
//   xor8    : DPP row_ror:8          (i+8 mod 16 == i^8)
//   xor16/32: v_permlane16/32_swap   (gfx950; swap(x,x) pair-sum == x + x^m)
//   xor4    : no DPP/permlane form -> single ds_swizzle (BitMode 0x101F)
typedef unsigned int uint2v __attribute__((ext_vector_type(2)));

__device__ __forceinline__ float swz_xor4(float x) {
  return __int_as_float(__builtin_amdgcn_ds_swizzle(__float_as_int(x), 0x101F));
}
__device__ __forceinline__ float red_xor1(float x) {  // quad_perm [1,0,3,2]
  return x + __int_as_float(__builtin_amdgcn_mov_dpp(__float_as_int(x), 0xB1, 0xF, 0xF, true));
}
__device__ __forceinline__ float red_xor2(float x) {  // quad_perm [2,3,0,1]
  return x + __int_as_float(__builtin_amdgcn_mov_dpp(__float_as_int(x), 0x4E, 0xF, 0xF, true));
}
__device__ __forceinline__ float red_xor4(float x) { return x + swz_xor4(x); }
__device__ __forceinline__ float red_xor8(float x) {  // row_ror:8
  return x + __int_as_float(__builtin_amdgcn_mov_dpp(__float_as_int(x), 0x128, 0xF, 0xF, true));
}
__device__ __forceinline__ float red_xor16(float x) {
#if __has_builtin(__builtin_amdgcn_permlane16_swap)
  uint2v r = __builtin_amdgcn_permlane16_swap(__float_as_uint(x), __float_as_uint(x), false, false);
  return __uint_as_float(r.x) + __uint_as_float(r.y);
#else
  return x + __shfl_xor(x, 16);
#endif
}
__device__ __forceinline__ float red_xor32(float x) {
#if __has_builtin(__builtin_amdgcn_permlane32_swap)
  uint2v r = __builtin_amdgcn_permlane32_swap(__float_as_uint(x), __float_as_uint(x), false, false);
  return __uint_as_float(r.x) + __uint_as_float(r.y);
#else
  return x + __shfl_xor(x, 32);
#endif
}

// ---------------- pre-pass: per-(b,t) scalars ----------------
// S[(b*T+t)*HV + hv] = { eg, beta*rk, eg*rk, rq*SCALE }
__global__ __launch_bounds__(256) void gdn_prepass(
    const float* __restrict__ A_log, const float* __restrict__ a_in,
    const float* __restrict__ dt_bias, const float* __restrict__ q_in,
    const float* __restrict__ k_in, const float* __restrict__ b_in,
    float4* __restrict__ S)
{
  const int bt = blockIdx.x * 4 + (threadIdx.x >> 6);  // 4 bt per block
  const int lane = threadIdx.x & 63;
  const int h  = lane >> 4;           // 16 lanes per head
  const int j0 = (lane & 15) * 8;

  const float* kp = k_in + ((long)bt * Hn + h) * Kn + j0;
  const float* qp = q_in + ((long)bt * Hn + h) * Kn + j0;
  const float4 ka = *(const float4*)kp;
  const float4 kb = *(const float4*)(kp + 4);
  const float4 qa = *(const float4*)qp;
  const float4 qb = *(const float4*)(qp + 4);

  float ks = ka.x*ka.x + ka.y*ka.y + ka.z*ka.z + ka.w*ka.w
           + kb.x*kb.x + kb.y*kb.y + kb.z*kb.z + kb.w*kb.w;
  float qs = qa.x*qa.x + qa.y*qa.y + qa.z*qa.z + qa.w*qa.w
           + qb.x*qb.x + qb.y*qb.y + qb.z*qb.z + qb.w*qb.w;
  ks = red_xor1(ks); qs = red_xor1(qs);
  ks = red_xor2(ks); qs = red_xor2(qs);
  ks = red_xor4(ks); qs = red_xor4(qs);
  ks = red_xor8(ks); qs = red_xor8(qs);
  const float rk = rsqrtf(ks + 1e-6f);
  const float rq = rsqrtf(qs + 1e-6f);

  // broadcast rk/rq of head (lane&7)>>1 to the low 8 lanes
  const int src = (((lane & 7) >> 1) << 4);
  const float rkh = __shfl(rk, src);
  const float rqh = __shfl(rq, src);

  if (lane < 8) {
    const int hv = lane;
    const long sidx = (long)bt * HVn + hv;
    const float x  = a_in[sidx] + dt_bias[hv];
    const float sp = (x <= 20.0f) ? log1pf(expf(x)) : x;   // softplus
    const float eg = expf(-expf(A_log[hv]) * sp);
    const float beta = 1.0f / (1.0f + expf(-b_in[sidx]));
    S[sidx] = make_float4(eg, beta * rkh, eg * rkh, rqh * SCALE);
  }
}

// ---------------- recurrent scan ----------------
__device__ __forceinline__ void dot3_4(const float4 h, const float4 k, const float4 q,
                                       float& d1a, float& d1b,
                                       float& d2a, float& d2b,
                                       float& d3a, float& d3b) {
  d1a = fmaf(h.x, k.x, d1a); d1b = fmaf(h.y, k.y, d1b);
  d1a = fmaf(h.z, k.z, d1a); d1b = fmaf(h.w, k.w, d1b);
  d2a = fmaf(h.x, q.x, d2a); d2b = fmaf(h.y, q.y, d2b);
  d2a = fmaf(h.z, q.z, d2a); d2b = fmaf(h.w, q.w, d2b);
  d3a = fmaf(k.x, q.x, d3a); d3b = fmaf(k.y, q.y, d3b);
  d3a = fmaf(k.z, q.z, d3a); d3b = fmaf(k.w, q.w, d3b);
}

// 2048 blocks (V split 32-way) -> 2 waves/SIMD so the remaining latency
// (xor4 DS round, load waits, FMA chains) cross-hides between waves.
// Lane layout: kk = lane>>2 in [0,16) (8 state rows), vv = lane&3 (1 v-col).
__global__ __launch_bounds__(64, 2) void gdn_recurrent(
    const float* __restrict__ q_in, const float* __restrict__ k_in,
    const float* __restrict__ v_in, const float4* __restrict__ S,
    const float* __restrict__ h0_src, const int* __restrict__ h0_idx,
    float* __restrict__ out)
{
  const int blk = blockIdx.x;
  const int g    = (blk & 7) + ((blk >> 8) << 3);  // (b,hv) in [0,64), XCD-grouped
  const int vblk = (blk >> 3) & 31;
  const int b  = g >> 3;
  const int hv = g & 7;
  const int h  = hv >> 1;          // GQA rep=2
  const int lane = threadIdx.x;
  const int kk = lane >> 2;        // k-split [0,16), 8 rows each
  const int vv = lane & 3;
  const int vg = vblk * 4 + vv;
  const int k0 = kk * 8;

  const float* kbase = k_in + (((long)b * Tn) * Hn + h) * Kn + k0;
  const float* qbase = q_in + (((long)b * Tn) * Hn + h) * Kn + k0;
  const float* vbase = v_in + (((long)b * Tn) * HVn + hv) * Vn + vg;
  const float4* sbase = S + (long)b * Tn * HVn + hv;
  float* obase = out + (((long)b * Tn) * HVn + hv) * Vn + vg;

  // rotating 4-deep register prefetch
  float4 kb[DEPTH][2], qb[DEPTH][2], sb[DEPTH];
  float  vb[DEPTH];

#define LOAD_SLOT(p, tt)                                                   \
  {                                                                        \
    const int tc = (tt) < Tn ? (tt) : Tn - 1;                              \
    const float4* kp = (const float4*)(kbase + (long)tc * (Hn * Kn));      \
    const float4* qp = (const float4*)(qbase + (long)tc * (Hn * Kn));      \
    kb[p][0] = kp[0]; kb[p][1] = kp[1];                                    \
    qb[p][0] = qp[0]; qb[p][1] = qp[1];                                    \
    vb[p] = vbase[(long)tc * (HVn * Vn)];                                  \
    sb[p] = sbase[(long)tc * HVn];                                         \
  }

  LOAD_SLOT(0, 0) LOAD_SLOT(1, 1) LOAD_SLOT(2, 2) LOAD_SLOT(3, 3)

  // state: 8 rows x 1 column per lane
  float4 hs0, hs1;
  const int idx = h0_idx[b];
  if (idx >= 0) {
    const float* hp = h0_src + (((long)idx * HVn + hv) * Kn + k0) * Vn + vg;
    hs0 = make_float4(hp[0*Vn], hp[1*Vn], hp[2*Vn], hp[3*Vn]);
    hs1 = make_float4(hp[4*Vn], hp[5*Vn], hp[6*Vn], hp[7*Vn]);
  } else {
    hs0 = hs1 = make_float4(0.f, 0.f, 0.f, 0.f);
  }

  for (int t0 = 0; t0 < Tn; t0 += DEPTH) {
#pragma unroll
    for (int p = 0; p < DEPTH; ++p) {
      const int t = t0 + p;

      const float4 tk0 = kb[p][0], tk1 = kb[p][1];
      const float4 tq0 = qb[p][0], tq1 = qb[p][1];
      const float  tv  = vb[p];
      const float4 ts  = sb[p];
      const float c1 = ts.x, c2 = ts.y, c3 = ts.z, c4 = ts.w;

      // -- three dots from h_prev, k_raw, q_raw (24 fma, 6 chains) --
      float d1a = 0.f, d1b = 0.f, d2a = 0.f, d2b = 0.f, d3a = 0.f, d3b = 0.f;
      dot3_4(hs0, tk0, tq0, d1a, d1b, d2a, d2b, d3a, d3b);
      dot3_4(hs1, tk1, tq1, d1a, d1b, d2a, d2b, d3a, d3b);
      float d1 = d1a + d1b, d2 = d2a + d2b, d3 = d3a + d3b;

      // -- issue the single DS round (xor4) immediately --
      const float s1 = swz_xor4(d1), s2 = swz_xor4(d2), s3 = swz_xor4(d3);

      // -- prefetch slot p for t+DEPTH; pin with a scheduler barrier --
      LOAD_SLOT(p, t + DEPTH)
      __builtin_amdgcn_sched_barrier(0);

      // -- decay muls (independent of the reduction) fill the DS shadow --
      float4 hm0, hm1;
      hm0.x = hs0.x * c1; hm0.y = hs0.y * c1; hm0.z = hs0.z * c1; hm0.w = hs0.w * c1;
      hm1.x = hs1.x * c1; hm1.y = hs1.y * c1; hm1.z = hs1.z * c1; hm1.w = hs1.w * c1;

      // -- finish reduction over kk: xor4 (DS) + xor8/16/32 (VALU-class) --
      d1 += s1; d2 += s2; d3 += s3;
      d1 = red_xor8(d1);  d2 = red_xor8(d2);  d3 = red_xor8(d3);
      d1 = red_xor16(d1); d2 = red_xor16(d2); d3 = red_xor16(d3);
      d1 = red_xor32(d1); d2 = red_xor32(d2); d3 = red_xor32(d3);

      const float up = (tv - c3 * d1) * c2;        // rk * u
      const float o  = fmaf(c1, d2, up * d3) * c4; // (eg*d2 + u'*d3) * rq*scale

      hs0.x = fmaf(tk0.x, up, hm0.x); hs0.y = fmaf(tk0.y, up, hm0.y);
      hs0.z = fmaf(tk0.z, up, hm0.z); hs0.w = fmaf(tk0.w, up, hm0.w);
      hs1.x = fmaf(tk1.x, up, hm1.x); hs1.y = fmaf(tk1.y, up, hm1.y);
      hs1.z = fmaf(tk1.z, up, hm1.z); hs1.w = fmaf(tk1.w, up, hm1.w);

      if (lane < 4)                                 // kk==0 lanes, 4 contiguous
        obase[(long)t * (HVn * Vn)] = o;
    }
  }
#undef LOAD_SLOT
}

extern "C" void kernel_launch(void* const* d_in, const int* in_sizes, int n_in,
                              void* d_out, int out_size, void* d_ws, size_t ws_size,
                              hipStream_t stream) {
  const float* A_log = (const float*)d_in[0];
  const float* a_in  = (const float*)d_in[1];
  const float* dtb   = (const float*)d_in[2];
  const float* q_in  = (const float*)d_in[3];
  const float* k_in  = (const float*)d_in[4];
  const float* v_in  = (const float*)d_in[5];
  const float* b_in  = (const float*)d_in[6];
  const float* h0    = (const float*)d_in[7];
  const int*   idx   = (const int*)d_in[8];
  float* out = (float*)d_out;
  float4* S  = (float4*)d_ws;     // B*T*HV float4 = 4 MB

  gdn_prepass<<<dim3(Bn * Tn / 4), dim3(256), 0, stream>>>(A_log, a_in, dtb,
                                                           q_in, k_in, b_in, S);
  gdn_recurrent<<<dim3(2048), dim3(64), 0, stream>>>(q_in, k_in, v_in, S,
                                                     h0, idx, out);
}

// Round 2
// 1880.861 us; speedup vs baseline: 1.2713x; 1.2408x over previous
//
#include <hip/hip_runtime.h>
#include <math.h>

namespace {
constexpr int Bn = 8, Tn = 4096, Hn = 4, HVn = 8, Kn = 128, Vn = 128;
constexpr int CH = 16;            // timesteps staged per LDS chunk
constexpr int NCH = Tn / CH;      // 256 chunks
constexpr float SCALE = 0.088388347648318447f;  // 128^-0.5
}

// ---------------- DPP cross-lane add (VALU-class, no DS latency) ----------
// 0xB1 = quad_perm[1,0,3,2] (xor1), 0x4E = quad_perm[2,3,0,1] (xor2),
// 0x141 = row_half_mirror (i^7: valid xor4 substitute AFTER quads reduced),
// 0x140 = row_mirror (i^15: valid xor8 substitute AFTER 8-groups reduced).
template <int CTRL>
__device__ __forceinline__ float red_dpp(float x) {
  return x + __int_as_float(
      __builtin_amdgcn_mov_dpp(__float_as_int(x), CTRL, 0xF, 0xF, true));
}

// ---------------- pre-pass: per-(b,t) scalars ----------------
// S[(b*T+t)*HV + hv] = { eg, beta*rk, eg*rk, rq*SCALE }
__global__ __launch_bounds__(256) void gdn_prepass(
    const float* __restrict__ A_log, const float* __restrict__ a_in,
    const float* __restrict__ dt_bias, const float* __restrict__ q_in,
    const float* __restrict__ k_in, const float* __restrict__ b_in,
    float4* __restrict__ S)
{
  const int bt = blockIdx.x * 4 + (threadIdx.x >> 6);  // 4 bt per block
  const int lane = threadIdx.x & 63;
  const int h  = lane >> 4;           // 16 lanes per head
  const int j0 = (lane & 15) * 8;

  const float* kp = k_in + ((long)bt * Hn + h) * Kn + j0;
  const float* qp = q_in + ((long)bt * Hn + h) * Kn + j0;
  const float4 ka = *(const float4*)kp;
  const float4 kb = *(const float4*)(kp + 4);
  const float4 qa = *(const float4*)qp;
  const float4 qb = *(const float4*)(qp + 4);

  float ks = ka.x*ka.x + ka.y*ka.y + ka.z*ka.z + ka.w*ka.w
           + kb.x*kb.x + kb.y*kb.y + kb.z*kb.z + kb.w*kb.w;
  float qs = qa.x*qa.x + qa.y*qa.y + qa.z*qa.z + qa.w*qa.w
           + qb.x*qb.x + qb.y*qb.y + qb.z*qb.z + qb.w*qb.w;
  // reduce over 16 lanes: xor1, xor2, half_mirror(=xor4 coset), mirror(=xor8 coset)
  ks = red_dpp<0xB1>(ks);  qs = red_dpp<0xB1>(qs);
  ks = red_dpp<0x4E>(ks);  qs = red_dpp<0x4E>(qs);
  ks = red_dpp<0x141>(ks); qs = red_dpp<0x141>(qs);
  ks = red_dpp<0x140>(ks); qs = red_dpp<0x140>(qs);
  const float rk = rsqrtf(ks + 1e-6f);
  const float rq = rsqrtf(qs + 1e-6f);

  // broadcast rk/rq of head (lane&7)>>1 to the low 8 lanes
  const int src = (((lane & 7) >> 1) << 4);
  const float rkh = __shfl(rk, src);
  const float rqh = __shfl(rq, src);

  if (lane < 8) {
    const int hv = lane;
    const long sidx = (long)bt * HVn + hv;
    const float x  = a_in[sidx] + dt_bias[hv];
    const float sp = (x <= 20.0f) ? log1pf(expf(x)) : x;   // softplus
    const float eg = expf(-expf(A_log[hv]) * sp);
    const float beta = 1.0f / (1.0f + expf(-b_in[sidx]));
    S[sidx] = make_float4(eg, beta * rkh, eg * rkh, rqh * SCALE);
  }
}

// ---------------- recurrent scan ----------------
__device__ __forceinline__ void gll4(const float* g, float* l) {
  // width-4 global->LDS: lane i writes LDS base + i*4, reads g (per-lane addr)
  __builtin_amdgcn_global_load_lds(
      (const __attribute__((address_space(1))) void*)g,
      (__attribute__((address_space(3))) void*)l, 4, 0, 0);
}

__device__ __forceinline__ void dot3_4(const float4 h, const float4 k, const float4 q,
                                       float& d1a, float& d1b,
                                       float& d2a, float& d2b,
                                       float& d3a, float& d3b) {
  d1a = fmaf(h.x, k.x, d1a); d1b = fmaf(h.y, k.y, d1b);
  d1a = fmaf(h.z, k.z, d1a); d1b = fmaf(h.w, k.w, d1b);
  d2a = fmaf(h.x, q.x, d2a); d2b = fmaf(h.y, q.y, d2b);
  d2a = fmaf(h.z, q.z, d2a); d2b = fmaf(h.w, q.w, d2b);
  d3a = fmaf(k.x, q.x, d3a); d3b = fmaf(k.y, q.y, d3b);
  d3a = fmaf(k.z, q.z, d3a); d3b = fmaf(k.w, q.w, d3b);
}
__device__ __forceinline__ void upd4(float4& h, const float4 k,
                                     const float c1, const float up) {
  h.x = fmaf(k.x, up, h.x * c1); h.y = fmaf(k.y, up, h.y * c1);
  h.z = fmaf(k.z, up, h.z * c1); h.w = fmaf(k.w, up, h.w * c1);
}

__device__ __forceinline__ float step_compute(float4 (&hs)[4],
    const float4 (&fk)[4], const float4 (&fq)[4],
    const float tv, const float4 ts) {
  const float c1 = ts.x, c2 = ts.y, c3 = ts.z, c4 = ts.w;
  float d1a=0.f,d1b=0.f,d2a=0.f,d2b=0.f,d3a=0.f,d3b=0.f;
#pragma unroll
  for (int i = 0; i < 4; ++i)
    dot3_4(hs[i], fk[i], fq[i], d1a,d1b,d2a,d2b,d3a,d3b);
  float d1 = d1a + d1b, d2 = d2a + d2b, d3 = d3a + d3b;
  // reduce over kk (lane bits 0-2): 3 all-DPP rounds, ~24cy chain, no DS
  d1 = red_dpp<0xB1>(d1);  d2 = red_dpp<0xB1>(d2);  d3 = red_dpp<0xB1>(d3);
  d1 = red_dpp<0x4E>(d1);  d2 = red_dpp<0x4E>(d2);  d3 = red_dpp<0x4E>(d3);
  d1 = red_dpp<0x141>(d1); d2 = red_dpp<0x141>(d2); d3 = red_dpp<0x141>(d3);
  const float up = (tv - c3 * d1) * c2;        // rk * u
  const float o  = fmaf(c1, d2, up * d3) * c4; // (eg*d2 + u'*d3) * rq*scale
#pragma unroll
  for (int i = 0; i < 4; ++i) upd4(hs[i], fk[i], c1, up);
  return o;
}

// 1024 blocks = 64 (b,hv) x 16 v-splits; 1 wave/block; 4 blocks/CU (1/SIMD).
// Lane layout: kk = lane&7 (16 k-rows each, strided), vv = lane>>3 (1 v-col).
// k,q staged 16 steps/chunk in LDS (double-buffered, global_load_lds);
// v,S register-prefetched 8 steps deep.
__global__ __launch_bounds__(64, 1) void gdn_recurrent(
    const float* __restrict__ q_in, const float* __restrict__ k_in,
    const float* __restrict__ v_in, const float4* __restrict__ S,
    const float* __restrict__ h0_src, const int* __restrict__ h0_idx,
    float* __restrict__ out)
{
  const int blk  = blockIdx.x;
  const int g    = blk & 63;       // (b,hv): the 16 v-split sharers of one (b,hv)
  const int vblk = blk >> 6;       // land on the same XCD (same blk%8)
  const int b  = g >> 3;
  const int hv = g & 7;
  const int h  = hv >> 1;          // GQA rep=2
  const int lane = threadIdx.x;
  const int kk  = lane & 7;
  const int vv  = lane >> 3;
  const int vg  = vblk * 8 + vv;
  const int kk4 = kk * 4;

  __shared__ __align__(16) float sm[2][2][CH][Kn];  // [buf][k/q][t][128] = 32 KB

  const float* kg  = k_in + (((long)b * Tn) * Hn + h) * Kn + lane;  // +lane: gll src
  const float* qg  = q_in + (((long)b * Tn) * Hn + h) * Kn + lane;
  const float* vbp = v_in + (((long)b * Tn) * HVn + hv) * Vn + vg;
  const float4* sbp = S + (long)b * Tn * HVn + hv;
  float* obp = out + (((long)b * Tn) * HVn + hv) * Vn + vg;

#define STAGE(bf_, t0_) {                                           \
    const float* kp_ = kg + (long)(t0_) * (Hn * Kn);                \
    const float* qp_ = qg + (long)(t0_) * (Hn * Kn);                \
    _Pragma("unroll")                                               \
    for (int i_ = 0; i_ < CH; ++i_) {                               \
      gll4(kp_,      &sm[bf_][0][i_][0]);                           \
      gll4(kp_ + 64, &sm[bf_][0][i_][64]);                          \
      gll4(qp_,      &sm[bf_][1][i_][0]);                           \
      gll4(qp_ + 64, &sm[bf_][1][i_][64]);                          \
      kp_ += Hn * Kn; qp_ += Hn * Kn; } }

  // lane kk owns k-rows {32i + 4kk + m}: each ds_read_b128 group covers one
  // contiguous 128B segment (8 lanes x 16B) -> bank-conflict-free; vv copies broadcast.
#define LDFRAG(fk_, fq_, bf_, tt_) {                                \
    _Pragma("unroll")                                               \
    for (int i_ = 0; i_ < 4; ++i_) {                                \
      fk_[i_] = *(const float4*)&sm[bf_][0][tt_][i_ * 32 + kk4];    \
      fq_[i_] = *(const float4*)&sm[bf_][1][tt_][i_ * 32 + kk4]; } }

#define LOAD_VS(p_, tt_) {                                          \
    const int tc_ = (tt_) < Tn ? (tt_) : Tn - 1;                    \
    vbuf[p_] = vbp[(unsigned)(tc_ * (HVn * Vn))];                   \
    sbuf[p_] = sbp[(unsigned)(tc_ * HVn)]; }

  // state: 16 rows x 1 col per lane; row(i,m) = 32i + 4kk + m
  float4 hs[4];
  {
    const int idx = h0_idx[b];
    if (idx >= 0) {
      const float* hp = h0_src + (((long)idx * HVn + hv) * Kn + kk4) * Vn + vg;
#pragma unroll
      for (int i = 0; i < 4; ++i)
        hs[i] = make_float4(hp[(i*32 + 0) * Vn], hp[(i*32 + 1) * Vn],
                            hp[(i*32 + 2) * Vn], hp[(i*32 + 3) * Vn]);
    } else {
#pragma unroll
      for (int i = 0; i < 4; ++i) hs[i] = make_float4(0.f, 0.f, 0.f, 0.f);
    }
  }

  float  vbuf[8];
  float4 sbuf[8];

  // prologue: stage chunk 0, fill v/S pipeline (8 deep)
  STAGE(0, 0)
#pragma unroll
  for (int p = 0; p < 8; ++p) LOAD_VS(p, p)

  float4 fka[4], fqa[4], fkb[4], fqb[4];

  for (int c = 0; c < NCH; ++c) {
    const int t0 = c * CH;
    const int bf = c & 1;
    // all but the 16 newest (v/S lead) retired => chunk c's stage complete
    asm volatile("s_waitcnt vmcnt(16)" ::: "memory");
    if (c + 1 < NCH) STAGE((c + 1) & 1, t0 + CH)
    LDFRAG(fka, fqa, bf, 0)
#pragma unroll
    for (int u = 0; u < CH; u += 2) {
      LDFRAG(fkb, fqb, bf, u + 1)
      {
        const float o0 = step_compute(hs, fka, fqa, vbuf[u & 7], sbuf[u & 7]);
        if (kk == 0) obp[(unsigned)((t0 + u) * (HVn * Vn))] = o0;
      }
      LOAD_VS(u & 7, t0 + u + 8)
      if (u + 2 < CH) LDFRAG(fka, fqa, bf, u + 2)
      {
        const float o1 = step_compute(hs, fkb, fqb, vbuf[(u + 1) & 7], sbuf[(u + 1) & 7]);
        if (kk == 0) obp[(unsigned)((t0 + u + 1) * (HVn * Vn))] = o1;
      }
      LOAD_VS((u + 1) & 7, t0 + u + 9)
    }
  }
#undef STAGE
#undef LDFRAG
#undef LOAD_VS
}

extern "C" void kernel_launch(void* const* d_in, const int* in_sizes, int n_in,
                              void* d_out, int out_size, void* d_ws, size_t ws_size,
                              hipStream_t stream) {
  const float* A_log = (const float*)d_in[0];
  const float* a_in  = (const float*)d_in[1];
  const float* dtb   = (const float*)d_in[2];
  const float* q_in  = (const float*)d_in[3];
  const float* k_in  = (const float*)d_in[4];
  const float* v_in  = (const float*)d_in[5];
  const float* b_in  = (const float*)d_in[6];
  const float* h0    = (const float*)d_in[7];
  const int*   idx   = (const int*)d_in[8];
  float* out = (float*)d_out;
  float4* S  = (float4*)d_ws;     // B*T*HV float4 = 4 MB

  gdn_prepass<<<dim3(Bn * Tn / 4), dim3(256), 0, stream>>>(A_log, a_in, dtb,
                                                           q_in, k_in, b_in, S);
  gdn_recurrent<<<dim3(1024), dim3(64), 0, stream>>>(q_in, k_in, v_in, S,
                                                     h0, idx, out);
}

// Round 3
// 1435.960 us; speedup vs baseline: 1.6652x; 1.3098x over previous
//
#include <hip/hip_runtime.h>
#include <math.h>

namespace {
constexpr int Bn = 8, Tn = 4096, Hn = 4, HVn = 8, Kn = 128, Vn = 128;
constexpr int CH = 8;             // timesteps staged per LDS chunk
constexpr float SCALE = 0.088388347648318447f;  // 128^-0.5
}

typedef float f2 __attribute__((ext_vector_type(2)));

// ---------------- DPP cross-lane add (VALU-class, no DS latency) ----------
// 0xB1 = quad_perm[1,0,3,2] (xor1), 0x4E = quad_perm[2,3,0,1] (xor2),
// 0x141 = row_half_mirror (i^7: xor4 substitute AFTER quads reduced),
// 0x140 = row_mirror (i^15: xor8 substitute AFTER 8-groups reduced).
template <int CTRL>
__device__ __forceinline__ float red_dpp(float x) {
  return x + __int_as_float(
      __builtin_amdgcn_mov_dpp(__float_as_int(x), CTRL, 0xF, 0xF, true));
}

// ---------------- pre-pass: per-(b,t) scalars ----------------
// S[(b*T+t)*HV + hv] = { eg, beta*rk, eg*rk, rq*SCALE }
__global__ __launch_bounds__(256) void gdn_prepass(
    const float* __restrict__ A_log, const float* __restrict__ a_in,
    const float* __restrict__ dt_bias, const float* __restrict__ q_in,
    const float* __restrict__ k_in, const float* __restrict__ b_in,
    float4* __restrict__ S)
{
  const int bt = blockIdx.x * 4 + (threadIdx.x >> 6);  // 4 bt per block
  const int lane = threadIdx.x & 63;
  const int h  = lane >> 4;           // 16 lanes per head
  const int j0 = (lane & 15) * 8;

  const float* kp = k_in + ((long)bt * Hn + h) * Kn + j0;
  const float* qp = q_in + ((long)bt * Hn + h) * Kn + j0;
  const float4 ka = *(const float4*)kp;
  const float4 kb = *(const float4*)(kp + 4);
  const float4 qa = *(const float4*)qp;
  const float4 qb = *(const float4*)(qp + 4);

  float ks = ka.x*ka.x + ka.y*ka.y + ka.z*ka.z + ka.w*ka.w
           + kb.x*kb.x + kb.y*kb.y + kb.z*kb.z + kb.w*kb.w;
  float qs = qa.x*qa.x + qa.y*qa.y + qa.z*qa.z + qa.w*qa.w
           + qb.x*qb.x + qb.y*qb.y + qb.z*qb.z + qb.w*qb.w;
  ks = red_dpp<0xB1>(ks);  qs = red_dpp<0xB1>(qs);
  ks = red_dpp<0x4E>(ks);  qs = red_dpp<0x4E>(qs);
  ks = red_dpp<0x141>(ks); qs = red_dpp<0x141>(qs);
  ks = red_dpp<0x140>(ks); qs = red_dpp<0x140>(qs);
  const float rk = rsqrtf(ks + 1e-6f);
  const float rq = rsqrtf(qs + 1e-6f);

  // broadcast rk/rq of head (lane&7)>>1 to the low 8 lanes
  const int src = (((lane & 7) >> 1) << 4);
  const float rkh = __shfl(rk, src);
  const float rqh = __shfl(rq, src);

  if (lane < 8) {
    const int hv = lane;
    const long sidx = (long)bt * HVn + hv;
    const float x  = a_in[sidx] + dt_bias[hv];
    const float sp = (x <= 20.0f) ? log1pf(expf(x)) : x;   // softplus
    const float eg = expf(-expf(A_log[hv]) * sp);
    const float beta = 1.0f / (1.0f + expf(-b_in[sidx]));
    S[sidx] = make_float4(eg, beta * rkh, eg * rkh, rqh * SCALE);
  }
}

// ---------------- recurrent scan ----------------
__device__ __forceinline__ void gll16(const float* g, float* l) {
  __builtin_amdgcn_global_load_lds(
      (const __attribute__((address_space(1))) void*)g,
      (__attribute__((address_space(3))) void*)l, 16, 0, 0);
}
__device__ __forceinline__ void gll4(const float* g, float* l) {
  __builtin_amdgcn_global_load_lds(
      (const __attribute__((address_space(1))) void*)g,
      (__attribute__((address_space(3))) void*)l, 4, 0, 0);
}

// one recurrence step; 8 state rows x 1 col per lane, packed f32 math
__device__ __forceinline__ float step2(f2 (&hs)[4],
    const float4 k0, const float4 k1, const float4 q0, const float4 q1,
    const float tv, const float4 ts)
{
  const f2 k0l = f2{k0.x,k0.y}, k0h = f2{k0.z,k0.w};
  const f2 k1l = f2{k1.x,k1.y}, k1h = f2{k1.z,k1.w};
  const f2 q0l = f2{q0.x,q0.y}, q0h = f2{q0.z,q0.w};
  const f2 q1l = f2{q1.x,q1.y}, q1h = f2{q1.z,q1.w};
  f2 d1 = f2{0.f,0.f}, d2 = f2{0.f,0.f}, d3 = f2{0.f,0.f};
  d1 = __builtin_elementwise_fma(hs[0], k0l, d1);
  d2 = __builtin_elementwise_fma(hs[0], q0l, d2);
  d3 = __builtin_elementwise_fma(k0l, q0l, d3);
  d1 = __builtin_elementwise_fma(hs[1], k0h, d1);
  d2 = __builtin_elementwise_fma(hs[1], q0h, d2);
  d3 = __builtin_elementwise_fma(k0h, q0h, d3);
  d1 = __builtin_elementwise_fma(hs[2], k1l, d1);
  d2 = __builtin_elementwise_fma(hs[2], q1l, d2);
  d3 = __builtin_elementwise_fma(k1l, q1l, d3);
  d1 = __builtin_elementwise_fma(hs[3], k1h, d1);
  d2 = __builtin_elementwise_fma(hs[3], q1h, d2);
  d3 = __builtin_elementwise_fma(k1h, q1h, d3);
  float s1 = d1.x + d1.y, s2 = d2.x + d2.y, s3 = d3.x + d3.y;
  // reduce over kk = lane&15: 4 all-DPP rounds, no DS ops on the chain
  s1 = red_dpp<0xB1>(s1);  s2 = red_dpp<0xB1>(s2);  s3 = red_dpp<0xB1>(s3);
  s1 = red_dpp<0x4E>(s1);  s2 = red_dpp<0x4E>(s2);  s3 = red_dpp<0x4E>(s3);
  s1 = red_dpp<0x141>(s1); s2 = red_dpp<0x141>(s2); s3 = red_dpp<0x141>(s3);
  s1 = red_dpp<0x140>(s1); s2 = red_dpp<0x140>(s2); s3 = red_dpp<0x140>(s3);
  const float c1 = ts.x;
  const float up = (tv - ts.z * s1) * ts.y;        // rk * u
  const float o  = fmaf(c1, s2, up * s3) * ts.w;   // (eg*d2 + u'*d3) * rq*scale
  const f2 c1v = f2{c1, c1}, upv = f2{up, up};
  hs[0] = __builtin_elementwise_fma(k0l, upv, hs[0] * c1v);
  hs[1] = __builtin_elementwise_fma(k0h, upv, hs[1] * c1v);
  hs[2] = __builtin_elementwise_fma(k1l, upv, hs[2] * c1v);
  hs[3] = __builtin_elementwise_fma(k1h, upv, hs[3] * c1v);
  return o;
}

// 2048 blocks = 64 (b,hv) x 32 v-splits; 1 wave/block; 8 blocks/CU (2/SIMD).
// Lane layout: kk = lane&15 (8 k-rows each), vv = lane>>4 (1 v-col).
// k,q: 8-step LDS chunks via gll16 (dbuf, const indices). v,S: one gll4/chunk
// (lanes 0-31 carry v, 32-63 carry S). Zero per-step VMEM loads.
__global__ __launch_bounds__(64, 2) void gdn_recurrent(
    const float* __restrict__ q_in, const float* __restrict__ k_in,
    const float* __restrict__ v_in, const float4* __restrict__ S,
    const float* __restrict__ h0_src, const int* __restrict__ h0_idx,
    float* __restrict__ out)
{
  const int blk  = blockIdx.x;
  const int g    = blk & 63;       // 32 v-split sharers of (b,hv) share an XCD
  const int vblk = blk >> 6;       // [0,32)
  const int b  = g >> 3;
  const int hv = g & 7;
  const int h  = hv >> 1;          // GQA rep=2
  const int lane = threadIdx.x;
  const int kk  = lane & 15;
  const int vv  = lane >> 4;
  const int vg  = vblk * 4 + vv;
  const int kk4 = kk * 4;

  __shared__ __align__(16) float smK[2][CH][Kn];   // 8 KB
  __shared__ __align__(16) float smQ[2][CH][Kn];   // 8 KB
  __shared__ __align__(16) float smVS[2][64];      // 512 B: [0..31]=v, [32..63]=S

  // staging sources: k/q rows (2 rows per gll16, lane>>5 picks row parity)
  const float* kst = k_in + (((long)b * Tn + (lane >> 5)) * Hn + h) * Kn + (lane & 31) * 4;
  const float* qst = q_in + (((long)b * Tn + (lane >> 5)) * Hn + h) * Kn + (lane & 31) * 4;
  const float* Sf  = (const float*)S;
  unsigned vsStride;
  const float* vsb;
  if (lane < 32) {                 // v slice: 8 t x 4 cols
    vsStride = HVn * Vn;
    vsb = v_in + (((long)b * Tn + (lane >> 2)) * HVn + hv) * Vn + vblk * 4 + (lane & 3);
  } else {                         // S: 8 t x 4 comps
    const int l2 = lane - 32;
    vsStride = HVn * 4;
    vsb = Sf + (((long)b * Tn + (l2 >> 2)) * HVn + hv) * 4 + (l2 & 3);
  }
  float* obp = out + (((long)b * Tn) * HVn + hv) * Vn + vg;

  // state: 8 rows x 1 col per lane; rows {i*64 + kk*4 + m}
  f2 hs[4];
  {
    const int idx = h0_idx[b];
    if (idx >= 0) {
      const float* hp = h0_src + (((long)idx * HVn + hv) * Kn) * Vn + vg;
      hs[0] = f2{hp[(kk4+0)*Vn],    hp[(kk4+1)*Vn]};
      hs[1] = f2{hp[(kk4+2)*Vn],    hp[(kk4+3)*Vn]};
      hs[2] = f2{hp[(64+kk4+0)*Vn], hp[(64+kk4+1)*Vn]};
      hs[3] = f2{hp[(64+kk4+2)*Vn], hp[(64+kk4+3)*Vn]};
    } else {
      hs[0] = hs[1] = hs[2] = hs[3] = f2{0.f, 0.f};
    }
  }

#define STAGE(DB, TS0) {                                              \
    const unsigned kqo = (unsigned)(TS0) * (unsigned)(Hn * Kn);       \
    _Pragma("unroll")                                                 \
    for (int j_ = 0; j_ < 4; ++j_) {                                  \
      gll16(kst + kqo + j_ * 1024, &smK[DB][2*j_][0]);                \
      gll16(qst + kqo + j_ * 1024, &smQ[DB][2*j_][0]);                \
    }                                                                 \
    gll4(vsb + (unsigned)(TS0) * vsStride, &smVS[DB][0]); }

#define LDFRAG(P, DB, TL) {                                           \
    P##k0 = *(const float4*)&smK[DB][TL][kk4];                        \
    P##k1 = *(const float4*)&smK[DB][TL][64 + kk4];                   \
    P##q0 = *(const float4*)&smQ[DB][TL][kk4];                        \
    P##q1 = *(const float4*)&smQ[DB][TL][64 + kk4];                   \
    P##v  = smVS[DB][(TL) * 4 + vv];                                  \
    P##s  = *(const float4*)&smVS[DB][32 + (TL) * 4]; }

#define SB __builtin_amdgcn_sched_barrier(0)
#define STORE(T, O) { if (kk == 0) obp[(unsigned)((T) * (HVn * Vn))] = (O); }

  float4 Ak0, Ak1, Aq0, Aq1, As; float Av;
  float4 Bk0, Bk1, Bq0, Bq1, Bs; float Bv;

  // prologue: stage chunk 0, drain, preload frag A for t=0
  STAGE(0, 0)
  asm volatile("s_waitcnt vmcnt(0)" ::: "memory");
  SB;
  LDFRAG(A, 0, 0)

  // chunk body: literal buffer index BF (const-folded LDS offsets so the
  // waitcnt pass can prove ds_read vs LDS-DMA no-alias). One counted
  // vmcnt(7) per chunk (7 = stores u0..u6 newer than next chunk's 9 glls).
#define BODY(BF, T0) {                                                          \
    const int ts0_ = ((T0) + CH < Tn) ? (T0) + CH : Tn - CH;                    \
    STAGE(BF ^ 1, ts0_)                                                         \
    SB;                                                                         \
    LDFRAG(B, BF, 1) SB; { const float o_ = step2(hs, Ak0,Ak1,Aq0,Aq1, Av, As); STORE((T0)+0, o_) } \
    LDFRAG(A, BF, 2) SB; { const float o_ = step2(hs, Bk0,Bk1,Bq0,Bq1, Bv, Bs); STORE((T0)+1, o_) } \
    LDFRAG(B, BF, 3) SB; { const float o_ = step2(hs, Ak0,Ak1,Aq0,Aq1, Av, As); STORE((T0)+2, o_) } \
    LDFRAG(A, BF, 4) SB; { const float o_ = step2(hs, Bk0,Bk1,Bq0,Bq1, Bv, Bs); STORE((T0)+3, o_) } \
    LDFRAG(B, BF, 5) SB; { const float o_ = step2(hs, Ak0,Ak1,Aq0,Aq1, Av, As); STORE((T0)+4, o_) } \
    LDFRAG(A, BF, 6) SB; { const float o_ = step2(hs, Bk0,Bk1,Bq0,Bq1, Bv, Bs); STORE((T0)+5, o_) } \
    LDFRAG(B, BF, 7) SB; { const float o_ = step2(hs, Ak0,Ak1,Aq0,Aq1, Av, As); STORE((T0)+6, o_) } \
    asm volatile("s_waitcnt vmcnt(7)" ::: "memory"); SB;                        \
    LDFRAG(A, BF ^ 1, 0) SB;                                                    \
    { const float o_ = step2(hs, Bk0,Bk1,Bq0,Bq1, Bv, Bs); STORE((T0)+7, o_) } }

  for (int t0 = 0; t0 < Tn; t0 += 2 * CH) {
    BODY(0, t0)
    BODY(1, t0 + CH)
  }
#undef BODY
#undef STAGE
#undef LDFRAG
#undef STORE
#undef SB
}

extern "C" void kernel_launch(void* const* d_in, const int* in_sizes, int n_in,
                              void* d_out, int out_size, void* d_ws, size_t ws_size,
                              hipStream_t stream) {
  const float* A_log = (const float*)d_in[0];
  const float* a_in  = (const float*)d_in[1];
  const float* dtb   = (const float*)d_in[2];
  const float* q_in  = (const float*)d_in[3];
  const float* k_in  = (const float*)d_in[4];
  const float* v_in  = (const float*)d_in[5];
  const float* b_in  = (const float*)d_in[6];
  const float* h0    = (const float*)d_in[7];
  const int*   idx   = (const int*)d_in[8];
  float* out = (float*)d_out;
  float4* S  = (float4*)d_ws;     // B*T*HV float4 = 4 MB

  gdn_prepass<<<dim3(Bn * Tn / 4), dim3(256), 0, stream>>>(A_log, a_in, dtb,
                                                           q_in, k_in, b_in, S);
  gdn_recurrent<<<dim3(2048), dim3(64), 0, stream>>>(q_in, k_in, v_in, S,
                                                     h0, idx, out);
}